// Round 1
// 136.460 us; speedup vs baseline: 1.0625x; 1.0625x over previous
//
#include <hip/hip_runtime.h>
#include <hip/hip_fp16.h>
#include <math.h>

// GraphLearner: per-edge cosine similarity + sigmoid + straight-through threshold.
//   out[e] = let v = sigmoid(cos(f1,f2)/T) in (v <= 0.5 ? 0 : v)
//
// R9 design (R8 post-mortem: edge kernel 62 µs = 512 MB of random 128-B row
// gathers at 8.26 TB/s effective; fp16 table (12.8 MB) misses the 4 MiB
// per-XCD L2 ~69% of the time -> ~353 MB/iter over the L3/fabric path = the
// wall. MLP arithmetic says we are NOT latency-bound, so the lever is bytes
// + L2 residency):
//  - Table switched fp16 -> int8 + per-node fp32 scale. Row 128 B -> 64 B
//    (gather 512 -> 256 MB), table 12.8 -> 6.4 MB (L2 hit ~31% -> ~60%).
//  - Quantization: q = rint(x * 127/max|x|), s = max|x|*inv/127. Error is
//    ABSOLUTE (<= s/2 ~ 7e-4/elem): dot err RMS ~6e-4, max over 2M edges
//    ~3e-3 < TAU=6e-3 -> the existing sign gate + bit-exact fp32 recompute
//    path (R3, passed) remains valid UNCHANGED at the same ~3.8% rate.
//  - Integer dot via v_dot4_i32_i8 (exact: |sum| <= 64*127^2 < 2^24), butter-
//    fly reduce in int (order-independent), cos8 = (float)idot * sA * sB.

#define D 64
#define BLOCK 256
#define COS_EPS 1e-6f
#define TAU 6e-3f
#define LOG2E 1.4426950408889634f

#define FMA4(A, X, Y) \
    A.x += X.x * Y.x; A.y += X.y * Y.y; A.z += X.z * Y.z; A.w += X.w * Y.w;

#define PAIRWISE8(E, O) \
    (((E.x + E.y) + (E.z + E.w)) + ((O.x + O.y) + (O.z + O.w)))

__device__ __forceinline__ int dot4_i8(unsigned a, unsigned b, int acc) {
#if __has_builtin(__builtin_amdgcn_sdot4)
    return __builtin_amdgcn_sdot4(a, b, acc, false);
#else
    #pragma unroll
    for (int i = 0; i < 4; ++i) {
        int ai = (int)((signed char)((a >> (8 * i)) & 0xff));
        int bi = (int)((signed char)((b >> (8 * i)) & 0xff));
        acc += ai * bi;
    }
    return acc;
#endif
}

__device__ __forceinline__ float read_temperature(const int* temp_ptr) {
    int tbits = *temp_ptr;
    if (tbits >= 1 && tbits < (1 << 23)) return (float)tbits;  // int32 temperature
    union { int i; float f; } u; u.i = tbits; return u.f;      // float32 bits
}

// Exact fp32 recompute for one edge, bit-identical to the R3 kernel (passed).
__device__ __forceinline__ float exact_cos(
    const float* __restrict__ node_embs,
    const float* __restrict__ dnorm,
    int i0, int i1, int lane)
{
    const float4* __restrict__ r0 = (const float4*)(node_embs + (size_t)i0 * D);
    const float4* __restrict__ r1 = (const float4*)(node_embs + (size_t)i1 * D);
    float4 x0 = r0[lane];
    float4 x1 = r0[lane + 8];
    float4 y0 = r1[lane];
    float4 y1 = r1[lane + 8];
    float pp = ((x0.x * y0.x + x0.y * y0.y) + (x0.z * y0.z + x0.w * y0.w))
             + ((x1.x * y1.x + x1.y * y1.y) + (x1.z * y1.z + x1.w * y1.w));
    #pragma unroll
    for (int m = 1; m < 8; m <<= 1) pp += __shfl_xor(pp, m, 8);
    return pp / (dnorm[i0] * dnorm[i1]);
}

// Kernel P: fused per-node norm (bit-exact numpy order) + int8-quantized row.
__global__ __launch_bounds__(BLOCK) void node_prep_kernel(
    const float*   __restrict__ node_embs,
    float*         __restrict__ dnorm,
    float*         __restrict__ nscale,
    unsigned int*  __restrict__ q8,      // 16 dwords (64 int8) per node
    int n_nodes)
{
    int n = blockIdx.x * BLOCK + threadIdx.x;
    if (n >= n_nodes) return;

    const float4* __restrict__ r = (const float4*)(node_embs + (size_t)n * D);

    float4 row[16];
    #pragma unroll
    for (int k = 0; k < 16; ++k) row[k] = r[k];

    // Clamped norm, bit-exact numpy pairwise order (unchanged from R2/R8).
    float4 z = make_float4(0.f, 0.f, 0.f, 0.f);
    float4 aE = z, aO = z;
    #pragma unroll
    for (int k = 0; k < 16; k += 2) {
        FMA4(aE, row[k], row[k])
        FMA4(aO, row[k + 1], row[k + 1])
    }
    float s = PAIRWISE8(aE, aO);
    float d = fmaxf(sqrtf(s), COS_EPS);
    dnorm[n] = d;
    float inv = 1.0f / d;

    // Row max |x| (order-free; only affects quantization, not exactness).
    float m0 = 0.f;
    #pragma unroll
    for (int k = 0; k < 16; ++k) {
        float4 a = row[k];
        m0 = fmaxf(m0, fmaxf(fmaxf(fabsf(a.x), fabsf(a.y)),
                             fmaxf(fabsf(a.z), fabsf(a.w))));
    }
    // q = rint(x * 127/m0)  (norm scale cancels);  decode scale on normalized
    // row: q * nscale ~= x*inv.  m0==0 -> all q=0, nscale=0 -> cos8=0 -> TAU
    // path -> exact recompute (safe).
    float kq = (m0 > 0.f) ? (127.0f / m0) : 0.f;
    nscale[n] = (m0 * inv) / 127.0f;

    unsigned int w[16];
    #pragma unroll
    for (int k = 0; k < 16; ++k) {
        float4 a = row[k];
        int q0 = (int)rintf(a.x * kq);
        int q1 = (int)rintf(a.y * kq);
        int q2 = (int)rintf(a.z * kq);
        int q3 = (int)rintf(a.w * kq);
        w[k] = (unsigned)(q0 & 255) | ((unsigned)(q1 & 255) << 8)
             | ((unsigned)(q2 & 255) << 16) | ((unsigned)(q3 & 255) << 24);
    }
    uint4* dst = (uint4*)(q8 + (size_t)n * 16);
    #pragma unroll
    for (int k = 0; k < 4; ++k)
        dst[k] = *(const uint4*)&w[k * 4];
}

// Kernel E: 8 lanes per group, 2 edges per group, int8 table (64 B rows).
__global__ __launch_bounds__(BLOCK) void GraphLearner_68513318306086_kernel(
    const float*        __restrict__ node_embs,
    const unsigned int* __restrict__ q8,
    const float*        __restrict__ nscale,
    const int*          __restrict__ edge_index,
    const float*        __restrict__ dnorm,
    const int*          __restrict__ temp_ptr,
    float*              __restrict__ out,
    int n_edges)
{
    int t    = blockIdx.x * BLOCK + threadIdx.x;
    int g    = t >> 3;              // group id: edges 2g, 2g+1
    int lane = threadIdx.x & 7;
    int e0   = g * 2;
    if (e0 >= n_edges) return;
    bool has1 = (e0 + 1) < n_edges;

    // One int2 per endpoint row covers both edges (E is even in this workload;
    // scalar fallback for a possible odd tail).
    int2 i0p, i1p;
    if (has1) {
        i0p = *(const int2*)(edge_index + e0);
        i1p = *(const int2*)(edge_index + n_edges + e0);
    } else {
        i0p.x = edge_index[e0];            i0p.y = i0p.x;
        i1p.x = edge_index[n_edges + e0];  i1p.y = i1p.x;
    }

    // 4 row gathers (uint2 = 8 int8 each) + 4 scale loads (hot 400 KB table).
    const uint2* __restrict__ tab = (const uint2*)q8;   // 8 uint2 per node
    uint2 A0 = tab[(i0p.x << 3) + lane];
    uint2 B0 = tab[(i1p.x << 3) + lane];
    uint2 A1 = tab[(i0p.y << 3) + lane];
    uint2 B1 = tab[(i1p.y << 3) + lane];
    float sA0 = nscale[i0p.x];
    float sB0 = nscale[i1p.x];
    float sA1 = nscale[i0p.y];
    float sB1 = nscale[i1p.y];

    // Exact integer dot (|sum| <= 64*127^2 < 2^24).
    int d0 = dot4_i8(A0.y, B0.y, dot4_i8(A0.x, B0.x, 0));
    int d1 = dot4_i8(A1.y, B1.y, dot4_i8(A1.x, B1.x, 0));

    // 3-level xor butterfly allreduce (int adds: order-independent, exact).
    #pragma unroll
    for (int m = 1; m < 8; m <<= 1) {
        d0 += __shfl_xor(d0, m, 8);
        d1 += __shfl_xor(d1, m, 8);
    }

    float cos0 = (float)d0 * (sA0 * sB0);
    float cos1 = (float)d1 * (sA1 * sB1);
    // Quant dot err max ~3e-3 < TAU -> sign safe outside TAU window; inside,
    // bit-exact fp32 recompute (identical to R3/R8, passed).
    if (fabsf(cos0) < TAU)
        cos0 = exact_cos(node_embs, dnorm, i0p.x, i1p.x, lane);
    if (has1 && fabsf(cos1) < TAU)
        cos1 = exact_cos(node_embs, dnorm, i0p.y, i1p.y, lane);

    if (lane < 2 && (lane == 0 || has1)) {
        float cosv = lane ? cos1 : cos0;
        float T    = read_temperature(temp_ptr);
        float invT = __builtin_amdgcn_rcpf(T);      // T=1 -> exactly 1.0
        float x    = cosv * invT;
        // Gate on sign(x): v<=0.5 <=> x<=0 exactly (sigmoid monotone, sig(0)=0.5).
        float ex   = __builtin_amdgcn_exp2f(-x * LOG2E);
        float v    = __builtin_amdgcn_rcpf(1.0f + ex);
        out[e0 + lane] = (x <= 0.0f) ? 0.0f : v;
    }
}

// Fallback (ws too small): 8 lanes/edge fp32, inline norms (R3 fallback, passed).
__global__ __launch_bounds__(BLOCK) void edge_kernel_fused(
    const float* __restrict__ node_embs,
    const int*   __restrict__ edge_index,
    const int*   __restrict__ temp_ptr,
    float*       __restrict__ out,
    int n_edges)
{
    int t    = blockIdx.x * BLOCK + threadIdx.x;
    int e    = t >> 3;
    int lane = threadIdx.x & 7;
    if (e >= n_edges) return;

    int i0 = edge_index[e];
    int i1 = edge_index[n_edges + e];

    const float4* __restrict__ r0 = (const float4*)(node_embs + (size_t)i0 * D);
    const float4* __restrict__ r1 = (const float4*)(node_embs + (size_t)i1 * D);

    float4 x0 = r0[lane];
    float4 x1 = r0[lane + 8];
    float4 y0 = r1[lane];
    float4 y1 = r1[lane + 8];

    float p  = ((x0.x * y0.x + x0.y * y0.y) + (x0.z * y0.z + x0.w * y0.w))
             + ((x1.x * y1.x + x1.y * y1.y) + (x1.z * y1.z + x1.w * y1.w));
    float a  = ((x0.x * x0.x + x0.y * x0.y) + (x0.z * x0.z + x0.w * x0.w))
             + ((x1.x * x1.x + x1.y * x1.y) + (x1.z * x1.z + x1.w * x1.w));
    float b  = ((y0.x * y0.x + y0.y * y0.y) + (y0.z * y0.z + y0.w * y0.w))
             + ((y1.x * y1.x + y1.y * y1.y) + (y1.z * y1.z + y1.w * y1.w));

    #pragma unroll
    for (int m = 1; m < 8; m <<= 1) {
        p += __shfl_xor(p, m, 8);
        a += __shfl_xor(a, m, 8);
        b += __shfl_xor(b, m, 8);
    }

    if (lane == 0) {
        float T    = read_temperature(temp_ptr);
        float d1   = fmaxf(sqrtf(a), COS_EPS);
        float d2   = fmaxf(sqrtf(b), COS_EPS);
        float cosv = p / (d1 * d2);
        float v    = 1.0f / (1.0f + expf(-(cosv / T)));
        out[e] = (v <= 0.5f) ? 0.0f : v;
    }
}

extern "C" void kernel_launch(void* const* d_in, const int* in_sizes, int n_in,
                              void* d_out, int out_size, void* d_ws, size_t ws_size,
                              hipStream_t stream) {
    const float* node_embs  = (const float*)d_in[0];
    const int*   edge_index = (const int*)d_in[1];
    const int*   temp_ptr   = (const int*)d_in[2];
    float*       out        = (float*)d_out;

    int n_nodes = in_sizes[0] / D;      // node_embs is [N, 64]
    int n_elems = in_sizes[0];
    int n_edges = in_sizes[1] / 2;      // edge_index is [2, E]

    size_t q8_bytes = (size_t)n_elems;                         // 6.4 MB
    size_t need = q8_bytes + (size_t)n_nodes * 2 * sizeof(float); // + 800 KB

    if (ws_size >= need) {
        unsigned int* q8     = (unsigned int*)d_ws;
        float*        nscale = (float*)((char*)d_ws + q8_bytes);
        float*        dnorm  = nscale + n_nodes;

        int grid_n = (n_nodes + BLOCK - 1) / BLOCK;
        node_prep_kernel<<<grid_n, BLOCK, 0, stream>>>(node_embs, dnorm, nscale, q8, n_nodes);

        int n_groups = (n_edges + 1) / 2;          // 2 edges per 8-lane group
        long long n_threads = (long long)n_groups * 8;
        int grid_e = (int)((n_threads + BLOCK - 1) / BLOCK);
        GraphLearner_68513318306086_kernel<<<grid_e, BLOCK, 0, stream>>>(
            node_embs, q8, nscale, edge_index, dnorm, temp_ptr, out, n_edges);
    } else {
        int grid_e = (int)(((long long)n_edges * 8 + BLOCK - 1) / BLOCK);
        edge_kernel_fused<<<grid_e, BLOCK, 0, stream>>>(
            node_embs, edge_index, temp_ptr, out, n_edges);
    }
}